// Round 10
// baseline (686.413 us; speedup 1.0000x reference)
//
#include <hip/hip_runtime.h>
#include <math.h>

#define T_LEN 3000
#define HID 64

typedef _Float16 f16;
typedef f16 f16x2 __attribute__((ext_vector_type(2)));
typedef f16 f16x8 __attribute__((ext_vector_type(8)));

#define NLOG2E  (-1.4426950408889634f)   // -log2(e)
#define N2LOG2E (-2.8853900817779268f)   // -2*log2(e)

__device__ __forceinline__ float bcast_lane(float v, int j) {
    return __builtin_bit_cast(float,
        __builtin_amdgcn_readlane(__builtin_bit_cast(int, v), j));
}

// intra-quad butterfly add: v += v[lane ^ (1 or 2)] via DPP quad_perm
template <int CTRL>
__device__ __forceinline__ float quad_xor_add(float v) {
    const int t = __builtin_amdgcn_mov_dpp(
        __builtin_bit_cast(int, v), CTRL, 0xf, 0xf, true);
    return v + __builtin_bit_cast(float, t);
}

// R16: matvec moved from MFMA back to dot2 -- but 4-way wave-split this time.
// R15 post-mortem: sched_barrier(0) regressed (+22cy) -> revert; R14 (490cy)
// is the scheduling floor of the MFMA design. Its MFMA segment costs
// ~130-140cy on the path (6 x 16cy wave-block + dep latency + accvgpr
// extract) while only 1/16 of each tile's rows is useful. Per wave the
// matvec is just 3072 MACs: as full-rate v_dot2_f32_f16 (VOP3P, 2cy/wave64
// like v_fma per m07) with unit=l>>2, K-quarter=l&3 (4 lanes/unit):
//   24 dot2 (48cy issue) + 2-stage intra-quad DPP butterfly (~24cy)
// = ~75cy, no AGPRs, no zero-C init. R7's dot2 failure was 96 dot2 on ONE
// wave (issue volume); the 4-way split fixes it exactly as it fixed MFMA in
// R11. Tail/barrier/x-window identical to R14.
// Falsification: >=613us => dot2 half-rate, revert to R14 = structural floor.
__global__ __launch_bounds__(256, 1)
void gru_qdot(
    const float* __restrict__ x,     // (B, T, 1)
    const float* __restrict__ W_ih,  // (192, 1)
    const float* __restrict__ W_hh,  // (192, 64)
    const float* __restrict__ b_ih,  // (192,)
    const float* __restrict__ b_hh,  // (192,)
    const float* __restrict__ W_fc,  // (1, 64)
    const float* __restrict__ b_fc,  // (1,)
    float* __restrict__ out)         // (B,)
{
    const int tid = threadIdx.x;
    const int w   = tid >> 6;        // wave 0..3 -> owns units 16w..16w+15
    const int l   = tid & 63;
    const int u   = 16 * w + (l >> 2);  // this lane's hidden unit
    const int k0  = 16 * (l & 3);       // this lane's K-quarter [k0, k0+16)
    const int b   = blockIdx.x;
    const long xbase = (long)b * T_LEN;

    __shared__ __align__(16) f16 hbuf[2][HID];  // double-buffered h (f16)
    __shared__ float hf32[HID];                 // epilogue (f32 exact)

    // ---- one-time: W_hh rows -> f16 pairs; lane (u, k-quarter) slice ----
    // Wd[g][p] = (W_hh[64g+u][k0+2p], W_hh[64g+u][k0+2p+1])
    f16x2 Wd[3][8];
#pragma unroll
    for (int g = 0; g < 3; ++g) {
        const float* p = W_hh + (size_t)(64 * g + u) * HID + k0;
        const float4 a = *reinterpret_cast<const float4*>(p);
        const float4 c = *reinterpret_cast<const float4*>(p + 4);
        const float4 d = *reinterpret_cast<const float4*>(p + 8);
        const float4 e = *reinterpret_cast<const float4*>(p + 12);
        Wd[g][0].x = (f16)a.x; Wd[g][0].y = (f16)a.y;
        Wd[g][1].x = (f16)a.z; Wd[g][1].y = (f16)a.w;
        Wd[g][2].x = (f16)c.x; Wd[g][2].y = (f16)c.y;
        Wd[g][3].x = (f16)c.z; Wd[g][3].y = (f16)c.w;
        Wd[g][4].x = (f16)d.x; Wd[g][4].y = (f16)d.y;
        Wd[g][5].x = (f16)d.z; Wd[g][5].y = (f16)d.w;
        Wd[g][6].x = (f16)e.x; Wd[g][6].y = (f16)e.y;
        Wd[g][7].x = (f16)e.z; Wd[g][7].y = (f16)e.w;
    }

    // per-unit scalars, pre-scaled by the exp2 constants (off-path fusion)
    const float wihr2 = W_ih[u]        * NLOG2E;
    const float wihz2 = W_ih[64 + u]   * NLOG2E;
    const float wihn2 = W_ih[128 + u]  * N2LOG2E;
    const float br2   = (b_ih[u]        + b_hh[u])        * NLOG2E;
    const float bz2   = (b_ih[64 + u]   + b_hh[64 + u])   * NLOG2E;
    const float bin2  = b_ih[128 + u]  * N2LOG2E;
    const float bhn2  = b_hh[128 + u]  * N2LOG2E;

    // x window in registers: lane j holds x[t0 + j]; broadcast via readlane
    float xwin = x[xbase + l];
    float xnxt = (64 + l < T_LEN) ? x[xbase + 64 + l] : 0.0f;

    if (tid < HID) hbuf[0][tid] = (f16)0.0f;
    __syncthreads();

    float h = 0.0f;  // this lane's unit value (fp32)

    // loop-invariant LDS read addresses: h[k0..k0+15] as 2x b128
    union HU { f16x8 v8; f16x2 v2[4]; };
    const f16x8* s0 = reinterpret_cast<const f16x8*>(hbuf[0]) + 2 * (l & 3);
    const f16x8* s1 = reinterpret_cast<const f16x8*>(hbuf[1]) + 2 * (l & 3);
    f16* d0 = &hbuf[0][u];
    f16* d1 = &hbuf[1][u];

    auto step = [&](const f16x8* srcP, f16* dstu, int t) {
        const int j = t & 63;

        // h fragment loads (2x ds_read_b128); latency-critical
        HU hlo, hhi;
        hlo.v8 = srcP[0];                 // h[k0 .. k0+7]
        hhi.v8 = srcP[1];                 // h[k0+8 .. k0+15]

        // fill the read-latency window (only needs xt)
        const float xt    = bcast_lane(xwin, j);
        const float pre_r = fmaf(xt, wihr2, br2);
        const float pre_z = fmaf(xt, wihz2, bz2);
        const float pre_n = fmaf(xt, wihn2, bin2);

        // 24 dot2, three 8-chains interleaved (6cy dep spacing >= 4cy)
        float sr = 0.f, sz = 0.f, sn = 0.f;
#pragma unroll
        for (int p = 0; p < 4; ++p) {
            sr = __builtin_amdgcn_fdot2(Wd[0][p], hlo.v2[p], sr, false);
            sz = __builtin_amdgcn_fdot2(Wd[1][p], hlo.v2[p], sz, false);
            sn = __builtin_amdgcn_fdot2(Wd[2][p], hlo.v2[p], sn, false);
        }
#pragma unroll
        for (int p = 0; p < 4; ++p) {
            sr = __builtin_amdgcn_fdot2(Wd[0][4 + p], hhi.v2[p], sr, false);
            sz = __builtin_amdgcn_fdot2(Wd[1][4 + p], hhi.v2[p], sz, false);
            sn = __builtin_amdgcn_fdot2(Wd[2][4 + p], hhi.v2[p], sn, false);
        }

        // intra-quad butterfly: full K-sum lands in all 4 lanes of the quad
        sr = quad_xor_add<0xB1>(sr);     // + lane^1
        sz = quad_xor_add<0xB1>(sz);
        sn = quad_xor_add<0xB1>(sn);
        sr = quad_xor_add<0x4E>(sr);     // + lane^2
        sz = quad_xor_add<0x4E>(sz);
        sn = quad_xor_add<0x4E>(sn);

        // minimal dependent tails (R14 structure, sr/sz/sn replace q*[0])
        const float r = __builtin_amdgcn_rcpf(
            1.0f + __builtin_amdgcn_exp2f(fmaf(sr, NLOG2E, pre_r)));
        const float hn2 = fmaf(sn, N2LOG2E, bhn2);
        const float z = __builtin_amdgcn_rcpf(
            1.0f + __builtin_amdgcn_exp2f(fmaf(sz, NLOG2E, pre_z)));
        const float zh  = z * h;
        const float omz = 1.0f - z;
        const float n = fmaf(2.0f, __builtin_amdgcn_rcpf(
            1.0f + __builtin_amdgcn_exp2f(fmaf(r, hn2, pre_n))), -1.0f);
        h = fmaf(omz, n, zh);   // (1-z)*n + z*h

        // write -> refill (rare, wave-uniform branch) -> barrier
        *dstu = (f16)h;         // 4 lanes/unit, same addr+value (benign)
        if (j == 63) {
            xwin = xnxt;                   // issued 64 steps ago -> landed
            const int idx = t + 65 + l;
            xnxt = (idx < T_LEN) ? x[xbase + idx] : 0.0f;
        }
        // LDS-only drain + barrier (no vmcnt drain -> x slack survives)
        asm volatile("s_waitcnt lgkmcnt(0)\n\ts_barrier" ::: "memory");
    };

    for (int t = 0; t < T_LEN; t += 2) {   // T_LEN even: clean pingpong
        step(s0, d1, t);
        step(s1, d0, t + 1);
    }

    // ---- epilogue: out[b] = h . W_fc + b_fc (fp32, exact register h) ----
    hf32[u] = h;   // unconditional, same value per u
    __syncthreads();
    if (tid < HID) {
        float v = hf32[tid] * W_fc[tid];
#pragma unroll
        for (int off = 32; off > 0; off >>= 1) v += __shfl_down(v, off);
        if (tid == 0) out[b] = v + b_fc[0];
    }
}

extern "C" void kernel_launch(void* const* d_in, const int* in_sizes, int n_in,
                              void* d_out, int out_size, void* d_ws, size_t ws_size,
                              hipStream_t stream) {
    const float* x    = (const float*)d_in[0];
    const float* W_ih = (const float*)d_in[1];
    const float* W_hh = (const float*)d_in[2];
    const float* b_ih = (const float*)d_in[3];
    const float* b_hh = (const float*)d_in[4];
    const float* W_fc = (const float*)d_in[5];
    const float* b_fc = (const float*)d_in[6];
    float* out = (float*)d_out;

    const int B = 256;  // in_sizes[0] = B*T = 768000 -> B=256, T=3000
    gru_qdot<<<B, 256, 0, stream>>>(x, W_ih, W_hh, b_ih, b_hh, W_fc, b_fc, out);
}

// Round 11
// 643.706 us; speedup vs baseline: 1.0663x; 1.0663x over previous
//
#include <hip/hip_runtime.h>
#include <math.h>

#define T_LEN 3000
#define HID 64

typedef _Float16 f16;
typedef f16 f16x8 __attribute__((ext_vector_type(8)));
typedef float f32x4 __attribute__((ext_vector_type(4)));

#define NLOG2E  (-1.4426950408889634f)   // -log2(e)
#define N2LOG2E (-2.8853900817779268f)   // -2*log2(e)

__device__ __forceinline__ float bcast_lane(float v, int j) {
    return __builtin_bit_cast(float,
        __builtin_amdgcn_readlane(__builtin_bit_cast(int, v), j));
}

// R17 = R14 (the measured optimum of 10 structural variants) + one fold.
// Variant ledger (cy/step): R7 1-wave MFMA 746 | R8 split-K 786 | R10
// bcast-MFMA 864 | R11 4-wave MFMA 497 | R12 2-batch 738(busy) | R13 C-seed
// 524 | R14 fused-tail 490 | R15 sched_barrier 512 | R16 4-wave dot2 530.
// Step chain: barrier -> ds_read(~120) -> 6-MFMA(~130) -> trans tail(~90)
// -> write -> drain(~40). Cross-wave h-exchange is unavoidable (K spans all
// 64 units); with B=#CUs, wall = stepcy*T (R12 theorem) -> only the step
// matters. All cheaper-matvec alternatives re-price worse under the
// 5x-validated issue/latency model. This is the structural floor.
// R17's sole change vs R14: final segment had rcp_n -> fma(2,.,-1) ->
// fma(omz,.,zh) (two dependent fmas after the last rcp). Fold:
//   h = omz*(2*rcn-1) + z*h = (2*omz)*rcn + (z*h - omz)
// t2=2*omz and zmh=z*h-omz depend only on z,h -> compute during the n-gate
// exp2/rcp latency; ONE fma remains after rcp_n (~5cy off the chain).
__global__ __launch_bounds__(256, 1)
void gru_floor(
    const float* __restrict__ x,     // (B, T, 1)
    const float* __restrict__ W_ih,  // (192, 1)
    const float* __restrict__ W_hh,  // (192, 64)
    const float* __restrict__ b_ih,  // (192,)
    const float* __restrict__ b_hh,  // (192,)
    const float* __restrict__ W_fc,  // (1, 64)
    const float* __restrict__ b_fc,  // (1,)
    float* __restrict__ out)         // (B,)
{
    const int tid = threadIdx.x;
    const int w   = tid >> 6;      // wave 0..3 -> owns units 16w..16w+15
    const int l   = tid & 63;
    const int col = l & 15;
    const int grp = l >> 4;        // k-group (redundant dim for gate math)
    const int u   = 16 * w + col;  // this lane's hidden unit
    const int b   = blockIdx.x;
    const long xbase = (long)b * T_LEN;

    __shared__ __align__(16) f16 hbuf[2][HID];  // double-buffered h (f16)
    __shared__ float hf32[HID];                 // epilogue (f32 exact)

    // ---- one-time: this wave's W_hh tiles -> B fragments (f16) ----
    // B slot (lane, elem j) = W_hh[64*g + 16*w + col][8*grp + 32*hf + j]
    f16x8 Bf[3][2];
#pragma unroll
    for (int g = 0; g < 3; ++g) {
#pragma unroll
        for (int hf = 0; hf < 2; ++hf) {
            const float* p = W_hh + (size_t)(64 * g + 16 * w + col) * HID
                           + 8 * grp + 32 * hf;
            const float4 a = *reinterpret_cast<const float4*>(p);
            const float4 c = *reinterpret_cast<const float4*>(p + 4);
            f16x8 v;
            v[0] = (f16)a.x; v[1] = (f16)a.y; v[2] = (f16)a.z; v[3] = (f16)a.w;
            v[4] = (f16)c.x; v[5] = (f16)c.y; v[6] = (f16)c.z; v[7] = (f16)c.w;
            Bf[g][hf] = v;
        }
    }

    // per-unit scalars, pre-scaled by the exp2 constants (off-path fusion)
    const float wihr2 = W_ih[u]        * NLOG2E;
    const float wihz2 = W_ih[64 + u]   * NLOG2E;
    const float wihn2 = W_ih[128 + u]  * N2LOG2E;
    const float br2   = (b_ih[u]        + b_hh[u])        * NLOG2E;
    const float bz2   = (b_ih[64 + u]   + b_hh[64 + u])   * NLOG2E;
    const float bin2  = b_ih[128 + u]  * N2LOG2E;
    const float bhn2  = b_hh[128 + u]  * N2LOG2E;

    // x window in registers: lane j holds x[t0 + j]; broadcast via readlane
    float xwin = x[xbase + l];
    float xnxt = (64 + l < T_LEN) ? x[xbase + 64 + l] : 0.0f;

    if (tid < HID) hbuf[0][tid] = (f16)0.0f;
    __syncthreads();

    float h = 0.0f;  // this lane's unit value (fp32)
    const f32x4 zf = {0.f, 0.f, 0.f, 0.f};

    // loop-invariant LDS addresses
    const f16x8* s0A = reinterpret_cast<const f16x8*>(hbuf[0]) + grp;
    const f16x8* s0B = s0A + 4;
    const f16x8* s1A = reinterpret_cast<const f16x8*>(hbuf[1]) + grp;
    const f16x8* s1B = s1A + 4;
    f16* d0 = &hbuf[0][u];
    f16* d1 = &hbuf[1][u];

    auto step = [&](const f16x8* aP, const f16x8* bP, f16* dstu, int t) {
        const int j = t & 63;

        const f16x8 A0 = *aP;             // h[8g..8g+7]       (ds_read_b128)
        const f16x8 A1 = *bP;             // h[32+8g..32+8g+7]

        // off-path pre-terms (only need xt; compute during ds_read latency)
        const float xt    = bcast_lane(xwin, j);
        const float pre_r = fmaf(xt, wihr2, br2);
        const float pre_z = fmaf(xt, wihz2, bz2);
        const float pre_n = fmaf(xt, wihn2, bin2);

        // 6 MFMAs (16cy wave-block each); dep pairs 3 slots apart
        f32x4 pr = __builtin_amdgcn_mfma_f32_16x16x32_f16(A0, Bf[0][0], zf, 0, 0, 0);
        f32x4 pz = __builtin_amdgcn_mfma_f32_16x16x32_f16(A0, Bf[1][0], zf, 0, 0, 0);
        f32x4 pn = __builtin_amdgcn_mfma_f32_16x16x32_f16(A0, Bf[2][0], zf, 0, 0, 0);
        f32x4 qr = __builtin_amdgcn_mfma_f32_16x16x32_f16(A1, Bf[0][1], pr, 0, 0, 0);
        f32x4 qz = __builtin_amdgcn_mfma_f32_16x16x32_f16(A1, Bf[1][1], pz, 0, 0, 0);
        f32x4 qn = __builtin_amdgcn_mfma_f32_16x16x32_f16(A1, Bf[2][1], pn, 0, 0, 0);

        // r-chain: fma -> exp2 -> add -> rcp
        const float r = __builtin_amdgcn_rcpf(
            1.0f + __builtin_amdgcn_exp2f(fmaf(qr[0], NLOG2E, pre_r)));
        // parallel with r-chain:
        const float hn2 = fmaf(qn[0], N2LOG2E, bhn2);
        const float z = __builtin_amdgcn_rcpf(
            1.0f + __builtin_amdgcn_exp2f(fmaf(qz[0], NLOG2E, pre_z)));
        const float omz = 1.0f - z;
        const float t2  = omz + omz;          // 2*(1-z)
        const float zmh = fmaf(z, h, -omz);   // z*h - (1-z)
        // n-chain after r: fma -> exp2 -> add -> rcp -> ONE fma
        const float rcn = __builtin_amdgcn_rcpf(
            1.0f + __builtin_amdgcn_exp2f(fmaf(r, hn2, pre_n)));
        h = fmaf(t2, rcn, zmh);   // = (1-z)*(2*rcn-1) + z*h

        // write -> refill (rare, wave-uniform branch) -> barrier
        *dstu = (f16)h;         // unconditional: 4 lanes, same addr+value
        if (j == 63) {
            xwin = xnxt;                   // issued 64 steps ago -> landed
            const int idx = t + 65 + l;
            xnxt = (idx < T_LEN) ? x[xbase + idx] : 0.0f;
        }
        // LDS-only drain + barrier (no vmcnt drain -> x slack survives)
        asm volatile("s_waitcnt lgkmcnt(0)\n\ts_barrier" ::: "memory");
    };

    for (int t = 0; t < T_LEN; t += 2) {   // T_LEN even: clean pingpong
        step(s0A, s0B, d1, t);
        step(s1A, s1B, d0, t + 1);
    }

    // ---- epilogue: out[b] = h . W_fc + b_fc (fp32, exact register h) ----
    hf32[u] = h;   // unconditional, same value per u
    __syncthreads();
    if (tid < HID) {
        float v = hf32[tid] * W_fc[tid];
#pragma unroll
        for (int off = 32; off > 0; off >>= 1) v += __shfl_down(v, off);
        if (tid == 0) out[b] = v + b_fc[0];
    }
}

extern "C" void kernel_launch(void* const* d_in, const int* in_sizes, int n_in,
                              void* d_out, int out_size, void* d_ws, size_t ws_size,
                              hipStream_t stream) {
    const float* x    = (const float*)d_in[0];
    const float* W_ih = (const float*)d_in[1];
    const float* W_hh = (const float*)d_in[2];
    const float* b_ih = (const float*)d_in[3];
    const float* b_hh = (const float*)d_in[4];
    const float* W_fc = (const float*)d_in[5];
    const float* b_fc = (const float*)d_in[6];
    float* out = (float*)d_out;

    const int B = 256;  // in_sizes[0] = B*T = 768000 -> B=256, T=3000
    gru_floor<<<B, 256, 0, stream>>>(x, W_ih, W_hh, b_ih, b_hh, W_fc, b_fc, out);
}